// Round 1
// baseline (123.711 us; speedup 1.0000x reference)
//
#include <hip/hip_runtime.h>
#include <math.h>

#define DD 8
#define MM 7
#define MOO 9
#define NPTS 100
#define EPSF 1e-5f

// ---------------- pack kernel: antecedents[r][0..7] -> 24-bit code ----------
__global__ __launch_bounds__(256) void pack_kernel(const int* __restrict__ ant,
                                                   unsigned* __restrict__ packed,
                                                   int R) {
    int r = blockIdx.x * 256 + threadIdx.x;
    if (r < R) {
        const int4* a = reinterpret_cast<const int4*>(ant) + (size_t)r * 2;
        int4 lo = a[0], hi = a[1];
        int v[8] = {lo.x, lo.y, lo.z, lo.w, hi.x, hi.y, hi.z, hi.w};
        unsigned code = 0u;
        #pragma unroll
        for (int i = 0; i < 8; ++i) {
            int c = v[i];
            c = (c < 0) ? 7 : (c > MM - 1 ? MM - 1 : c);   // -1 -> wildcard slot 7
            code |= (unsigned)c << (3 * i);
        }
        packed[r] = code;
    }
}

// ---------------- main kernel: one block per batch row ----------------------
template <bool USE_PACKED>
__global__ __launch_bounds__(256) void anfis_kernel(
    const float* __restrict__ x,
    const unsigned* __restrict__ packed,
    const int* __restrict__ ant,
    const int* __restrict__ consequents,
    const float* __restrict__ in_centers,   // [D][M]
    const float* __restrict__ in_widths,    // [D][M]
    const float* __restrict__ out_centers,  // [MO]
    const float* __restrict__ out_widths,   // [MO]
    float* __restrict__ out,
    int R)
{
    __shared__ float mu[64];        // [d][c], c==7 -> 1.0
    __shared__ float pairs[256];    // 4 tables x 64: mu[2p][c0]*mu[2p+1][c1]
    __shared__ float s0s[MOO], s1s[MOO];
    __shared__ float svals[256][9];
    __shared__ int   sidx[256][9];

    const int tid = threadIdx.x;
    const int b   = blockIdx.x;

    // --- membership table (64 entries) + defuzz constants (9 entries) ---
    if (tid < 64) {
        int d = tid >> 3, c = tid & 7;
        float v = 1.0f;
        if (c < MM) {
            float z = (x[b * DD + d] - in_centers[d * MM + c]) / in_widths[d * MM + c];
            v = expf(-0.5f * z * z);
            v = fminf(v, 1.0f);
            v = fmaxf(v, EPSF);
        }
        mu[tid] = v;
    } else if (tid < 64 + MOO) {
        int mo = tid - 64;
        float oc = out_centers[mo], ow = out_widths[mo];
        float s0 = 0.0f, s1 = 0.0f;
        for (int p = 0; p < NPTS; ++p) {
            float u = (float)p * (1.0f / 99.0f);
            float z = (u - oc) / ow;
            float e = expf(-0.5f * z * z);
            s0 += e;
            s1 += u * e;
        }
        s0s[mo] = s0;
        s1s[mo] = s1;
    }
    __syncthreads();

    // --- pair-product tables: firing = T0*T1*T2*T3 (4 lookups, 3 muls) ---
    {
        int p = tid >> 6, q = tid & 63;
        pairs[tid] = mu[(2 * p) * 8 + (q & 7)] * mu[(2 * p + 1) * 8 + (q >> 3)];
    }
    __syncthreads();

    // --- scan rules, keep per-thread top-8 (val desc, idx asc on ties) ---
    float vals[8];
    int   idxs[8];
    #pragma unroll
    for (int k = 0; k < 8; ++k) { vals[k] = -1.0f; idxs[k] = 0x7fffffff; }

    if (USE_PACKED) {
        const uint4* pk4 = reinterpret_cast<const uint4*>(packed);
        const int iters = R >> 10;             // 4 rules/thread/iter * 256 threads
        for (int j = 0; j < iters; ++j) {
            uint4 cd = pk4[j * 256 + tid];
            unsigned codes[4] = {cd.x, cd.y, cd.z, cd.w};
            int rbase = (j * 256 + tid) * 4;
            #pragma unroll
            for (int s = 0; s < 4; ++s) {
                unsigned code = codes[s];
                float f = pairs[code & 63]
                        * pairs[64  + ((code >> 6)  & 63)]
                        * pairs[128 + ((code >> 12) & 63)]
                        * pairs[192 + ((code >> 18) & 63)];
                if (f > vals[7]) {              // strict: ties keep older (lower) index
                    float nv = f; int ni = rbase + s;
                    #pragma unroll
                    for (int k = 0; k < 8; ++k) {
                        bool take = nv > vals[k];
                        float cv = vals[k]; int ci = idxs[k];
                        vals[k] = take ? nv : cv;
                        idxs[k] = take ? ni : ci;
                        nv = take ? cv : nv;
                        ni = take ? ci : ni;
                    }
                }
            }
        }
        // tail (R not multiple of 1024) — indices still ascending per thread
        for (int r = (R >> 10) << 10; true; ) {
            int rr = r + tid;
            if (rr >= R) break;
            unsigned code = packed[rr];
            float f = pairs[code & 63]
                    * pairs[64  + ((code >> 6)  & 63)]
                    * pairs[128 + ((code >> 12) & 63)]
                    * pairs[192 + ((code >> 18) & 63)];
            if (f > vals[7]) {
                float nv = f; int ni = rr;
                #pragma unroll
                for (int k = 0; k < 8; ++k) {
                    bool take = nv > vals[k];
                    float cv = vals[k]; int ci = idxs[k];
                    vals[k] = take ? nv : cv;
                    idxs[k] = take ? ni : ci;
                    nv = take ? cv : nv;
                    ni = take ? ci : ni;
                }
            }
            r += 256;
        }
    } else {
        // fallback: pack inline from antecedents (no workspace available)
        for (int r = tid; r < R; r += 256) {
            const int4* a = reinterpret_cast<const int4*>(ant) + (size_t)r * 2;
            int4 lo = a[0], hi = a[1];
            int v[8] = {lo.x, lo.y, lo.z, lo.w, hi.x, hi.y, hi.z, hi.w};
            unsigned code = 0u;
            #pragma unroll
            for (int i = 0; i < 8; ++i) {
                int c = v[i];
                c = (c < 0) ? 7 : (c > MM - 1 ? MM - 1 : c);
                code |= (unsigned)c << (3 * i);
            }
            float f = pairs[code & 63]
                    * pairs[64  + ((code >> 6)  & 63)]
                    * pairs[128 + ((code >> 12) & 63)]
                    * pairs[192 + ((code >> 18) & 63)];
            if (f > vals[7]) {
                float nv = f; int ni = r;
                #pragma unroll
                for (int k = 0; k < 8; ++k) {
                    bool take = nv > vals[k];
                    float cv = vals[k]; int ci = idxs[k];
                    vals[k] = take ? nv : cv;
                    idxs[k] = take ? ni : ci;
                    nv = take ? cv : nv;
                    ni = take ? ci : ni;
                }
            }
        }
    }

    // --- block-wide top-8 via LDS tree merge (stable: val desc, idx asc) ---
    #pragma unroll
    for (int k = 0; k < 8; ++k) { svals[tid][k] = vals[k]; sidx[tid][k] = idxs[k]; }

    for (int off = 128; off >= 1; off >>= 1) {
        __syncthreads();
        if (tid < off) {
            float ov[8]; int oi[8];
            int pa = 0, pb = 0;
            #pragma unroll
            for (int k = 0; k < 8; ++k) {
                float va = svals[tid][pa];        int ia = sidx[tid][pa];
                float vb = svals[tid + off][pb];  int ib = sidx[tid + off][pb];
                bool ta = (va > vb) || ((va == vb) && (ia < ib));
                ov[k] = ta ? va : vb;
                oi[k] = ta ? ia : ib;
                pa += ta ? 1 : 0;
                pb += ta ? 0 : 1;
            }
            #pragma unroll
            for (int k = 0; k < 8; ++k) { svals[tid][k] = ov[k]; sidx[tid][k] = oi[k]; }
        }
    }
    __syncthreads();

    // --- defuzzify: out = sum v*S1[c] / (sum v*S0[c] + eps) ---
    if (tid == 0) {
        float num = 0.0f, den = 0.0f;
        #pragma unroll
        for (int k = 0; k < 8; ++k) {
            float v = svals[0][k];
            int   c = consequents[sidx[0][k]];
            num += v * s1s[c];
            den += v * s0s[c];
        }
        out[b] = num / (den + EPSF);
    }
}

extern "C" void kernel_launch(void* const* d_in, const int* in_sizes, int n_in,
                              void* d_out, int out_size, void* d_ws, size_t ws_size,
                              hipStream_t stream) {
    const float* x      = (const float*)d_in[0];
    const int*   ant    = (const int*)d_in[1];
    const int*   cons   = (const int*)d_in[2];
    const float* in_c   = (const float*)d_in[3];
    const float* in_w   = (const float*)d_in[4];
    const float* out_c  = (const float*)d_in[5];
    const float* out_w  = (const float*)d_in[6];
    float*       out    = (float*)d_out;

    const int B = in_sizes[0] / DD;
    const int R = in_sizes[1] / DD;

    const bool use_ws = (d_ws != nullptr) && (ws_size >= (size_t)R * sizeof(unsigned));

    if (use_ws) {
        unsigned* packed = (unsigned*)d_ws;
        pack_kernel<<<(R + 255) / 256, 256, 0, stream>>>(ant, packed, R);
        anfis_kernel<true><<<B, 256, 0, stream>>>(x, packed, ant, cons, in_c, in_w,
                                                  out_c, out_w, out, R);
    } else {
        anfis_kernel<false><<<B, 256, 0, stream>>>(x, nullptr, ant, cons, in_c, in_w,
                                                   out_c, out_w, out, R);
    }
}

// Round 2
// 85.475 us; speedup vs baseline: 1.4473x; 1.4473x over previous
//
#include <hip/hip_runtime.h>
#include <math.h>

#define DD 8
#define MM 7
#define MOO 9
#define NPTS 100
#define EPSF 1e-5f

#define THREADS 512
#define RPT 64            // rules per thread (fast path)
#define ITERS 16          // RPT/4
#define CAP 512           // candidate buffer capacity

// ---------------- pack kernel: antecedents[r][0..7] -> 24-bit code ----------
__global__ __launch_bounds__(256) void pack_kernel(const int* __restrict__ ant,
                                                   unsigned* __restrict__ packed,
                                                   int R) {
    int r = blockIdx.x * 256 + threadIdx.x;
    if (r < R) {
        const int4* a = reinterpret_cast<const int4*>(ant) + (size_t)r * 2;
        int4 lo = a[0], hi = a[1];
        int v[8] = {lo.x, lo.y, lo.z, lo.w, hi.x, hi.y, hi.z, hi.w};
        unsigned code = 0u;
        #pragma unroll
        for (int i = 0; i < 8; ++i) {
            int c = v[i];
            c = (c < 0) ? 7 : (c > MM - 1 ? MM - 1 : c);   // -1 -> wildcard slot 7
            code |= (unsigned)c << (3 * i);
        }
        packed[r] = code;
    }
}

// ---------------- fast kernel: one block (512 thr) per batch row ------------
// Exact two-phase top-8: pass1 evaluates all rules into registers tracking only
// the per-thread max; threshold M8 = 8th largest of the 512 thread maxes
// (provably <= true 8th value); pass2 re-scans registers (no LDS) pushing the
// ~8-16 candidates >= M8; exact rank selection with (val desc, idx asc).
__global__ __launch_bounds__(THREADS, 4) void anfis_fast(
    const float* __restrict__ x,
    const unsigned* __restrict__ packed,
    const int* __restrict__ consequents,
    const float* __restrict__ in_centers,   // [D][M]
    const float* __restrict__ in_widths,    // [D][M]
    const float* __restrict__ out_centers,  // [MO]
    const float* __restrict__ out_widths,   // [MO]
    float* __restrict__ out)
{
    __shared__ float mu[64];          // [d][c], c==7 -> 1.0
    __shared__ float pairs[256];      // 4 x 64 pair products
    __shared__ float quads[8192];     // 2 x 4096 quad products
    __shared__ float s0s[MOO], s1s[MOO];
    __shared__ float smax[THREADS];
    __shared__ float sthr;
    __shared__ int   scnt;
    __shared__ float cvals[CAP];
    __shared__ int   cidx[CAP];
    __shared__ float wv[8];
    __shared__ int   wc[8];

    const int tid = threadIdx.x;
    const int b   = blockIdx.x;

    // --- phase 0: membership table + defuzz constants ---
    if (tid < 64) {
        int d = tid >> 3, c = tid & 7;
        float v = 1.0f;
        if (c < MM) {
            float z = (x[b * DD + d] - in_centers[d * MM + c]) / in_widths[d * MM + c];
            v = expf(-0.5f * z * z);
            v = fminf(v, 1.0f);
            v = fmaxf(v, EPSF);
        }
        mu[tid] = v;
    } else if (tid < 64 + MOO) {
        int mo = tid - 64;
        float oc = out_centers[mo], ow = out_widths[mo];
        float s0 = 0.0f, s1 = 0.0f;
        for (int p = 0; p < NPTS; ++p) {
            float u = (float)p * (1.0f / 99.0f);
            float z = (u - oc) / ow;
            float e = expf(-0.5f * z * z);
            s0 += e;
            s1 += u * e;
        }
        s0s[mo] = s0;
        s1s[mo] = s1;
    }
    __syncthreads();

    // --- phase 1: pair products (4 tables x 64) ---
    if (tid < 256) {
        int p = tid >> 6, q = tid & 63;
        pairs[tid] = mu[(2 * p) * 8 + (q & 7)] * mu[(2 * p + 1) * 8 + (q >> 3)];
    }
    __syncthreads();

    // --- phase 2: quad products (2 tables x 4096) ---
    #pragma unroll
    for (int k = tid; k < 8192; k += THREADS) {
        int t = k & 4095, hi = k >> 12;      // hi in {0,1}
        quads[k] = pairs[hi * 128 + (t & 63)] * pairs[hi * 128 + 64 + ((t >> 6) & 63)];
    }
    if (tid == 0) scnt = 0;
    __syncthreads();

    // --- phase 3: evaluate all rules into registers, track per-thread max ---
    const uint4* pk4 = reinterpret_cast<const uint4*>(packed);
    float vals[RPT];
    float mymax = -1.0f;
    #pragma unroll
    for (int j = 0; j < ITERS; ++j) {
        uint4 cd = pk4[j * THREADS + tid];
        unsigned codes[4] = {cd.x, cd.y, cd.z, cd.w};
        #pragma unroll
        for (int s = 0; s < 4; ++s) {
            unsigned code = codes[s];
            float f = quads[code & 4095u] * quads[4096u + ((code >> 12) & 4095u)];
            vals[j * 4 + s] = f;
            mymax = fmaxf(mymax, f);
        }
    }
    smax[tid] = mymax;
    __syncthreads();

    // --- phase 4: wave 0 extracts the 8th-largest thread max -> threshold ---
    if (tid < 64) {
        float m[8];
        #pragma unroll
        for (int k = 0; k < 8; ++k) m[k] = smax[tid + 64 * k];
        float thr = -1.0f;
        #pragma unroll
        for (int round = 0; round < 8; ++round) {
            float lm = m[0];
            #pragma unroll
            for (int k = 1; k < 8; ++k) lm = fmaxf(lm, m[k]);
            float wm = lm;
            #pragma unroll
            for (int off = 32; off >= 1; off >>= 1)
                wm = fmaxf(wm, __shfl_xor(wm, off, 64));
            unsigned long long bal = __ballot(lm == wm);
            int first = (int)__ffsll(bal) - 1;
            if (tid == first) {                 // remove exactly one instance
                bool done = false;
                #pragma unroll
                for (int k = 0; k < 8; ++k) {
                    bool rm = (!done) && (m[k] == wm);
                    m[k] = rm ? -2.0f : m[k];
                    done = done || rm;
                }
            }
            thr = wm;
        }
        if (tid == 0) sthr = thr;
    }
    __syncthreads();

    // --- phase 5: register re-scan, push candidates >= threshold ---
    {
        const float thr = sthr;
        #pragma unroll
        for (int j = 0; j < ITERS; ++j) {
            bool any = false;
            #pragma unroll
            for (int s = 0; s < 4; ++s) any = any || (vals[j * 4 + s] >= thr);
            if (__any((int)any)) {
                #pragma unroll
                for (int s = 0; s < 4; ++s) {
                    float v = vals[j * 4 + s];
                    if (v >= thr) {
                        int pos = atomicAdd(&scnt, 1);
                        if (pos < CAP) {
                            cvals[pos] = v;
                            cidx[pos]  = (j * THREADS + tid) * 4 + s;
                        }
                    }
                }
            }
        }
    }
    __syncthreads();

    // --- phase 6: exact rank selection among candidates (val desc, idx asc) ---
    if (tid < 64) {
        int n = scnt < CAP ? scnt : CAP;
        for (int c = tid; c < n; c += 64) {
            float v = cvals[c];
            int   id = cidx[c];
            int r = 0;
            for (int mI = 0; mI < n; ++mI) {
                float vm = cvals[mI];
                int   im = cidx[mI];
                r += ((vm > v) || (vm == v && im < id)) ? 1 : 0;
            }
            if (r < 8) {
                wv[r] = v;
                wc[r] = consequents[id];
            }
        }
    }
    __syncthreads();

    // --- phase 7: defuzzify ---
    if (tid == 0) {
        float num = 0.0f, den = 0.0f;
        #pragma unroll
        for (int k = 0; k < 8; ++k) {
            num += wv[k] * s1s[wc[k]];
            den += wv[k] * s0s[wc[k]];
        }
        out[b] = num / (den + EPSF);
    }
}

// ---------------- generic fallback (round-1 kernel, inline pack) ------------
__global__ __launch_bounds__(256) void anfis_kernel(
    const float* __restrict__ x,
    const int* __restrict__ ant,
    const int* __restrict__ consequents,
    const float* __restrict__ in_centers,
    const float* __restrict__ in_widths,
    const float* __restrict__ out_centers,
    const float* __restrict__ out_widths,
    float* __restrict__ out,
    int R)
{
    __shared__ float mu[64];
    __shared__ float pairs[256];
    __shared__ float s0s[MOO], s1s[MOO];
    __shared__ float svals[256][9];
    __shared__ int   sidx[256][9];

    const int tid = threadIdx.x;
    const int b   = blockIdx.x;

    if (tid < 64) {
        int d = tid >> 3, c = tid & 7;
        float v = 1.0f;
        if (c < MM) {
            float z = (x[b * DD + d] - in_centers[d * MM + c]) / in_widths[d * MM + c];
            v = expf(-0.5f * z * z);
            v = fminf(v, 1.0f);
            v = fmaxf(v, EPSF);
        }
        mu[tid] = v;
    } else if (tid < 64 + MOO) {
        int mo = tid - 64;
        float oc = out_centers[mo], ow = out_widths[mo];
        float s0 = 0.0f, s1 = 0.0f;
        for (int p = 0; p < NPTS; ++p) {
            float u = (float)p * (1.0f / 99.0f);
            float z = (u - oc) / ow;
            float e = expf(-0.5f * z * z);
            s0 += e;
            s1 += u * e;
        }
        s0s[mo] = s0;
        s1s[mo] = s1;
    }
    __syncthreads();

    {
        int p = tid >> 6, q = tid & 63;
        pairs[tid] = mu[(2 * p) * 8 + (q & 7)] * mu[(2 * p + 1) * 8 + (q >> 3)];
    }
    __syncthreads();

    float vals[8];
    int   idxs[8];
    #pragma unroll
    for (int k = 0; k < 8; ++k) { vals[k] = -1.0f; idxs[k] = 0x7fffffff; }

    for (int r = tid; r < R; r += 256) {
        const int4* a = reinterpret_cast<const int4*>(ant) + (size_t)r * 2;
        int4 lo = a[0], hi = a[1];
        int v[8] = {lo.x, lo.y, lo.z, lo.w, hi.x, hi.y, hi.z, hi.w};
        unsigned code = 0u;
        #pragma unroll
        for (int i = 0; i < 8; ++i) {
            int c = v[i];
            c = (c < 0) ? 7 : (c > MM - 1 ? MM - 1 : c);
            code |= (unsigned)c << (3 * i);
        }
        float f = pairs[code & 63]
                * pairs[64  + ((code >> 6)  & 63)]
                * pairs[128 + ((code >> 12) & 63)]
                * pairs[192 + ((code >> 18) & 63)];
        if (f > vals[7]) {
            float nv = f; int ni = r;
            #pragma unroll
            for (int k = 0; k < 8; ++k) {
                bool take = nv > vals[k];
                float cv = vals[k]; int ci = idxs[k];
                vals[k] = take ? nv : cv;
                idxs[k] = take ? ni : ci;
                nv = take ? cv : nv;
                ni = take ? ci : ni;
            }
        }
    }

    #pragma unroll
    for (int k = 0; k < 8; ++k) { svals[tid][k] = vals[k]; sidx[tid][k] = idxs[k]; }

    for (int off = 128; off >= 1; off >>= 1) {
        __syncthreads();
        if (tid < off) {
            float ov[8]; int oi[8];
            int pa = 0, pb = 0;
            #pragma unroll
            for (int k = 0; k < 8; ++k) {
                float va = svals[tid][pa];        int ia = sidx[tid][pa];
                float vb = svals[tid + off][pb];  int ib = sidx[tid + off][pb];
                bool ta = (va > vb) || ((va == vb) && (ia < ib));
                ov[k] = ta ? va : vb;
                oi[k] = ta ? ia : ib;
                pa += ta ? 1 : 0;
                pb += ta ? 0 : 1;
            }
            #pragma unroll
            for (int k = 0; k < 8; ++k) { svals[tid][k] = ov[k]; sidx[tid][k] = oi[k]; }
        }
    }
    __syncthreads();

    if (tid == 0) {
        float num = 0.0f, den = 0.0f;
        #pragma unroll
        for (int k = 0; k < 8; ++k) {
            float v = svals[0][k];
            int   c = consequents[sidx[0][k]];
            num += v * s1s[c];
            den += v * s0s[c];
        }
        out[b] = num / (den + EPSF);
    }
}

extern "C" void kernel_launch(void* const* d_in, const int* in_sizes, int n_in,
                              void* d_out, int out_size, void* d_ws, size_t ws_size,
                              hipStream_t stream) {
    const float* x      = (const float*)d_in[0];
    const int*   ant    = (const int*)d_in[1];
    const int*   cons   = (const int*)d_in[2];
    const float* in_c   = (const float*)d_in[3];
    const float* in_w   = (const float*)d_in[4];
    const float* out_c  = (const float*)d_in[5];
    const float* out_w  = (const float*)d_in[6];
    float*       out    = (float*)d_out;

    const int B = in_sizes[0] / DD;
    const int R = in_sizes[1] / DD;

    const bool use_ws = (d_ws != nullptr) && (ws_size >= (size_t)R * sizeof(unsigned));
    const bool fast   = use_ws && (R == THREADS * 4 * ITERS);   // R == 32768

    if (fast) {
        unsigned* packed = (unsigned*)d_ws;
        pack_kernel<<<(R + 255) / 256, 256, 0, stream>>>(ant, packed, R);
        anfis_fast<<<B, THREADS, 0, stream>>>(x, packed, cons, in_c, in_w,
                                              out_c, out_w, out);
    } else {
        anfis_kernel<<<B, 256, 0, stream>>>(x, ant, cons, in_c, in_w,
                                            out_c, out_w, out, R);
    }
}